// Round 24
// baseline (47.894 us; speedup 1.0000x reference)
//
#include <hip/hip_runtime.h>

// ---------------------------------------------------------------------------
// FFT_Conv_Layer == 3x3 "same" spatial conv with flipped REAL filter plane:
//   out[b,o,y,x] = sum_{i,ky,kx} filts[0,i,o,ky,kx,0] * img[b,i,y+1-ky,x+1-kx]
//
// Ladder: R8 21.07 | R20 20.91 (champion). ~10-13us unattributed; suspect =
// per-launch/graph-node overhead. R21 tested ONE dispatch but had a bug:
// wf tap stride is 512 chunks * 16B = 8192 B, code used 2048 (halfs/bytes
// slip) -> 8 of 9 taps mis-addressed, absmax 1.6. R22 = R21 + that one fix.
// (R22/R23 benches lost to an unresponsive container; resubmitted unchanged.)
//
// Structure: R20 verbatim + per-block wf gather into LDS (512 threads shard
// 4608 chunks, 9/thread, filts L2-resident, overlapped with image staging).
// LDS 124,416 B (1 blk/CU, 2 waves/SIMD unchanged). K-loop: A+B from LDS.
// ---------------------------------------------------------------------------

typedef _Float16 f16x8 __attribute__((ext_vector_type(8)));
typedef float    f32x4 __attribute__((ext_vector_type(4)));

#define NB 16
#define NC 64
#define NH 64
#define NW 64
#define CHUNKS 528                 // 66 xp positions * 8 channel-chunks per slab
#define SLAB_BYTES (CHUNKS * 16)   // 8448 B per image row slab
#define IMG_LDS (6 * SLAB_BYTES)   // 50,688 B
#define WF_HALFS (9 * 2 * 4 * 64 * 8)  // 36,864 halfs = 73,728 B = 4608 chunks

// ---------------------------------------------------------------------------
// conv_one: 256 blocks (XCD-swizzled) = (b, 4-row quad), 8 waves (512 thr).
//   LDS: [0, 50688) image: 6 slabs = rows y0-1..y0+4, swizzled chunks
//        [50688, 124416) wf: chunk c = ((t*2+kc)*4+n)*64 + l at byte c*16.
//   Phase A (pre-barrier, overlapped): pads (tid<96), image 48 jobs
//     (8 coalesced f32 loads -> cvt -> swizzled ds_write_b128 each), wf
//     9 chunks/thread (72 strided f32 loads from L2-hot filts + 9 b128).
//   Phase B: wave w = (row w>>1, xh w&1) owns 32x x 64o: 2m x 4n frags.
//     Per (ky,kx,kc): 2 A ds_reads + 4 B ds_reads + 8 MFMA.
//   C/D layout (m89/m91-verified): o = n*16+(lane&15), x = m*16+(lane>>4)*4+j
// ---------------------------------------------------------------------------
__global__ __launch_bounds__(512, 1) void conv_one(const float* __restrict__ imgs,
                                                   const float* __restrict__ filts,
                                                   float* __restrict__ out) {
    __shared__ char lds[IMG_LDS + WF_HALFS * 2];   // 124,416 B
    char* wfl = lds + IMG_LDS;
    const int bid = blockIdx.x;
    const int swz = ((bid & 7) << 5) | (bid >> 3);   // bijective: 256 = 8*32
    const int b   = swz >> 4;
    const int y0  = (swz & 15) << 2;     // first of 4 output rows
    const int tid = threadIdx.x;
    const int w   = tid >> 6;            // wave 0..7
    const int l   = tid & 63;
    const int h   = l >> 4;              // k-chunk lane group
    const int r   = l & 15;              // A-row / B-col within fragment

    // ---- pads: 6 slabs x 16 chunks (xp = 0, 65) ----
    if (tid < 96) {
        const int sl  = tid >> 4;
        const int rem = tid & 15;
        const int ci  = rem >> 1;
        const int xp2 = (rem & 1) ? 65 : 0;
        const int c2  = xp2 * 8 + (ci ^ (xp2 & 7));
        f16x8 z;
        #pragma unroll
        for (int k = 0; k < 8; ++k) z[k] = (_Float16)0.f;
        *reinterpret_cast<f16x8*>(lds + sl * SLAB_BYTES + c2 * 16) = z;
    }

    // ---- image: stage 6 slabs (rows y0-1 .. y0+4), 48 jobs over 8 waves ----
    #pragma unroll
    for (int j = 0; j < 6; ++j) {
        const int job = w + j * 8;
        const int sl  = job >> 3;
        const int ci  = job & 7;
        const int yy  = y0 - 1 + sl;
        float fr[8];
        if ((unsigned)yy < (unsigned)NH) {
            const float* src = imgs + (((size_t)(b * NC + ci * 8)) * NH + yy) * NW + l;
            #pragma unroll
            for (int k = 0; k < 8; ++k) fr[k] = src[(size_t)k * NH * NW];
        } else {
            #pragma unroll
            for (int k = 0; k < 8; ++k) fr[k] = 0.f;
        }
        f16x8 v;
        #pragma unroll
        for (int k = 0; k < 8; ++k) v[k] = (_Float16)fr[k];
        const int xp = l + 1;
        const int chunk = xp * 8 + (ci ^ (xp & 7));
        *reinterpret_cast<f16x8*>(lds + sl * SLAB_BYTES + chunk * 16) = v;
    }

    // ---- wf: 4608 chunks sharded 9/thread (72 scalar L2 loads + 9 b128) ----
    #pragma unroll
    for (int q = 0; q < 9; ++q) {
        const int c  = tid * 9 + q;          // chunk index
        const int fl = c & 63;               // lane within fragment
        const int n  = (c >> 6) & 3;
        const int kc = (c >> 8) & 1;
        const int t  = c >> 9;               // 0..8
        const int o  = n * 16 + (fl & 15);
        const int i0 = kc * 32 + (fl >> 4) * 8;
        const float* src = filts + ((size_t)i0 * 64 + o) * 18 + t * 2;
        f16x8 v;
        #pragma unroll
        for (int e = 0; e < 8; ++e)
            v[e] = (_Float16)src[(size_t)e * 64 * 18];
        *reinterpret_cast<f16x8*>(wfl + c * 16) = v;
    }
    __syncthreads();

    const int row = w >> 1;              // output row within quad (0..3)
    const int xh  = w & 1;               // x half (0..1)

    f32x4 acc[2][4];
    #pragma unroll
    for (int m = 0; m < 2; ++m)
        #pragma unroll
        for (int n = 0; n < 4; ++n)
            acc[m][n] = f32x4{0.f, 0.f, 0.f, 0.f};

    #pragma unroll
    for (int ky = 0; ky < 3; ++ky) {
        const char* slab = lds + (row + 2 - ky) * SLAB_BYTES;   // sl in 0..5
        #pragma unroll
        for (int kx = 0; kx < 3; ++kx) {
            const int t = ky * 3 + kx;
            const char* wt = wfl + (size_t)t * 8192;   // 512 chunks * 16B per tap
            #pragma unroll
            for (int kc = 0; kc < 2; ++kc) {
                f16x8 a[2], bb[4];
                #pragma unroll
                for (int m = 0; m < 2; ++m) {
                    const int xp = xh * 32 + m * 16 + r + 2 - kx;  // 0..65
                    const int chunk = xp * 8 + (((kc << 2) + h) ^ (xp & 7));
                    a[m] = *reinterpret_cast<const f16x8*>(slab + chunk * 16);
                }
                #pragma unroll
                for (int n = 0; n < 4; ++n)
                    bb[n] = *reinterpret_cast<const f16x8*>(
                        wt + (size_t)(kc * 4 + n) * 1024 + l * 16);
                #pragma unroll
                for (int m = 0; m < 2; ++m)
                    #pragma unroll
                    for (int n = 0; n < 4; ++n)
                        acc[m][n] = __builtin_amdgcn_mfma_f32_16x16x32_f16(a[m], bb[n], acc[m][n], 0, 0, 0);
            }
        }
    }

    const int y = y0 + row;
    #pragma unroll
    for (int m = 0; m < 2; ++m) {
        const int x0 = xh * 32 + m * 16 + h * 4;
        #pragma unroll
        for (int n = 0; n < 4; ++n) {
            const int o = n * 16 + r;
            *reinterpret_cast<f32x4*>(out + (((size_t)(b * 64 + o) * 64 + y) * 64) + x0) = acc[m][n];
        }
    }
}

extern "C" void kernel_launch(void* const* d_in, const int* in_sizes, int n_in,
                              void* d_out, int out_size, void* d_ws, size_t ws_size,
                              hipStream_t stream) {
    const float* imgs  = (const float*)d_in[0];   // [16][64][64][64] f32
    const float* filts = (const float*)d_in[1];   // [1][64][64][3][3][2] f32
    float* out = (float*)d_out;                   // [16][64][64][64] f32
    (void)d_ws; (void)ws_size;                    // no workspace needed

    hipLaunchKernelGGL(conv_one, dim3(256), dim3(512), 0, stream, imgs, filts, out);
}

// Round 25
// 18.535 us; speedup vs baseline: 2.5840x; 2.5840x over previous
//
#include <hip/hip_runtime.h>

// ---------------------------------------------------------------------------
// FFT_Conv_Layer == 3x3 "same" spatial conv with flipped REAL filter plane:
//   out[b,o,y,x] = sum_{i,ky,kx} filts[0,i,o,ky,kx,0] * img[b,i,y+1-ky,x+1-kx]
//
// Ladder: R20 20.91 (2-dispatch champion) | R24 conv_one 47.9: launch
// overhead ~= 0 (dur_us ~= kernel time), and the per-block wf gather's
// uncoalesced loads (64 lines/wave-instr, ~600 MB L2) were the +29us.
// R25: same single-dispatch structure, gather COALESCED: thread reads
// f = tid+512k as float2 (consecutive entries, 512B/wave-instr, 75 MB L2
// total ~2us overlapped), decodes f->(i,o,t), scatters one half into the wf
// LDS layout via ds_write_u16 (read-side b128 unchanged).
// ---------------------------------------------------------------------------

typedef _Float16 f16x8 __attribute__((ext_vector_type(8)));
typedef float    f32x4 __attribute__((ext_vector_type(4)));

#define NB 16
#define NC 64
#define NH 64
#define NW 64
#define CHUNKS 528                 // 66 xp positions * 8 channel-chunks per slab
#define SLAB_BYTES (CHUNKS * 16)   // 8448 B per image row slab
#define IMG_LDS (6 * SLAB_BYTES)   // 50,688 B
#define WF_HALFS (9 * 2 * 4 * 64 * 8)  // 36,864 halfs = 73,728 B = 4608 chunks

// ---------------------------------------------------------------------------
// conv_one: 256 blocks (XCD-swizzled) = (b, 4-row quad), 8 waves (512 thr).
//   LDS: [0, 50688) image: 6 slabs = rows y0-1..y0+4, swizzled chunks
//        [50688, 124416) wf: chunk c = ((t*2+kc)*4+n)*64 + fl at byte c*16,
//          half e at byte c*16 + e*2.
//   Phase A (pre-barrier, overlapped):
//     - pads: tid<96 zero the xp=0,65 chunks of 6 slabs
//     - image: 48 jobs (slab j/8, ci j%8), 8 coalesced f32 loads -> cvt ->
//       swizzled ds_write_b128 each (chunk = xp*8 + (ci^(xp&7)))
//     - wf: 72 entries/thread, f = tid+512k: coalesced float2 load of
//       filts2[f] (= real part of entry f = i*576+o*9+t), decode, one
//       ds_write_u16 to c*8+e. 75MB L2 total, ~9-way write alias (cheap).
//   Phase B: wave w = (row w>>1, xh w&1) owns 32x x 64o: 2m x 4n frags.
//     Per (ky,kx,kc): 2 A ds_reads + 4 B ds_reads + 8 MFMA.
//   C/D layout (m89/m91-verified): o = n*16+(lane&15), x = m*16+(lane>>4)*4+j
// ---------------------------------------------------------------------------
__global__ __launch_bounds__(512, 1) void conv_one(const float* __restrict__ imgs,
                                                   const float* __restrict__ filts,
                                                   float* __restrict__ out) {
    __shared__ char lds[IMG_LDS + WF_HALFS * 2];   // 124,416 B
    char* wfl = lds + IMG_LDS;
    const int bid = blockIdx.x;
    const int swz = ((bid & 7) << 5) | (bid >> 3);   // bijective: 256 = 8*32
    const int b   = swz >> 4;
    const int y0  = (swz & 15) << 2;     // first of 4 output rows
    const int tid = threadIdx.x;
    const int w   = tid >> 6;            // wave 0..7
    const int l   = tid & 63;
    const int h   = l >> 4;              // k-chunk lane group
    const int r   = l & 15;              // A-row / B-col within fragment

    // ---- pads: 6 slabs x 16 chunks (xp = 0, 65) ----
    if (tid < 96) {
        const int sl  = tid >> 4;
        const int rem = tid & 15;
        const int ci  = rem >> 1;
        const int xp2 = (rem & 1) ? 65 : 0;
        const int c2  = xp2 * 8 + (ci ^ (xp2 & 7));
        f16x8 z;
        #pragma unroll
        for (int k = 0; k < 8; ++k) z[k] = (_Float16)0.f;
        *reinterpret_cast<f16x8*>(lds + sl * SLAB_BYTES + c2 * 16) = z;
    }

    // ---- image: stage 6 slabs (rows y0-1 .. y0+4), 48 jobs over 8 waves ----
    #pragma unroll
    for (int j = 0; j < 6; ++j) {
        const int job = w + j * 8;
        const int sl  = job >> 3;
        const int ci  = job & 7;
        const int yy  = y0 - 1 + sl;
        float fr[8];
        if ((unsigned)yy < (unsigned)NH) {
            const float* src = imgs + (((size_t)(b * NC + ci * 8)) * NH + yy) * NW + l;
            #pragma unroll
            for (int k = 0; k < 8; ++k) fr[k] = src[(size_t)k * NH * NW];
        } else {
            #pragma unroll
            for (int k = 0; k < 8; ++k) fr[k] = 0.f;
        }
        f16x8 v;
        #pragma unroll
        for (int k = 0; k < 8; ++k) v[k] = (_Float16)fr[k];
        const int xp = l + 1;
        const int chunk = xp * 8 + (ci ^ (xp & 7));
        *reinterpret_cast<f16x8*>(lds + sl * SLAB_BYTES + chunk * 16) = v;
    }

    // ---- wf: coalesced gather + LDS scatter (72 entries/thread) ----
    {
        const float2* filts2 = reinterpret_cast<const float2*>(filts);
        _Float16* wfh = reinterpret_cast<_Float16*>(wfl);
        #pragma unroll
        for (int k = 0; k < 72; ++k) {
            const int f = tid + k * 512;         // entry = i*576 + o*9 + t
            const float v = filts2[f].x;         // real plane
            const int i   = f / 576;
            const int rem = f - i * 576;
            const int o   = rem / 9;
            const int t   = rem - o * 9;
            const int kc = i >> 5, hh = (i >> 3) & 3, e = i & 7;
            const int n  = o >> 4,  rr = o & 15;
            const int c  = ((t * 2 + kc) * 4 + n) * 64 + hh * 16 + rr;
            wfh[c * 8 + e] = (_Float16)v;
        }
    }
    __syncthreads();

    const int row = w >> 1;              // output row within quad (0..3)
    const int xh  = w & 1;               // x half (0..1)

    f32x4 acc[2][4];
    #pragma unroll
    for (int m = 0; m < 2; ++m)
        #pragma unroll
        for (int n = 0; n < 4; ++n)
            acc[m][n] = f32x4{0.f, 0.f, 0.f, 0.f};

    #pragma unroll
    for (int ky = 0; ky < 3; ++ky) {
        const char* slab = lds + (row + 2 - ky) * SLAB_BYTES;   // sl in 0..5
        #pragma unroll
        for (int kx = 0; kx < 3; ++kx) {
            const int t = ky * 3 + kx;
            const char* wt = wfl + (size_t)t * 8192;   // 512 chunks * 16B per tap
            #pragma unroll
            for (int kc = 0; kc < 2; ++kc) {
                f16x8 a[2], bb[4];
                #pragma unroll
                for (int m = 0; m < 2; ++m) {
                    const int xp = xh * 32 + m * 16 + r + 2 - kx;  // 0..65
                    const int chunk = xp * 8 + (((kc << 2) + h) ^ (xp & 7));
                    a[m] = *reinterpret_cast<const f16x8*>(slab + chunk * 16);
                }
                #pragma unroll
                for (int n = 0; n < 4; ++n)
                    bb[n] = *reinterpret_cast<const f16x8*>(
                        wt + (size_t)(kc * 4 + n) * 1024 + l * 16);
                #pragma unroll
                for (int m = 0; m < 2; ++m)
                    #pragma unroll
                    for (int n = 0; n < 4; ++n)
                        acc[m][n] = __builtin_amdgcn_mfma_f32_16x16x32_f16(a[m], bb[n], acc[m][n], 0, 0, 0);
            }
        }
    }

    const int y = y0 + row;
    #pragma unroll
    for (int m = 0; m < 2; ++m) {
        const int x0 = xh * 32 + m * 16 + h * 4;
        #pragma unroll
        for (int n = 0; n < 4; ++n) {
            const int o = n * 16 + r;
            *reinterpret_cast<f32x4*>(out + (((size_t)(b * 64 + o) * 64 + y) * 64) + x0) = acc[m][n];
        }
    }
}

extern "C" void kernel_launch(void* const* d_in, const int* in_sizes, int n_in,
                              void* d_out, int out_size, void* d_ws, size_t ws_size,
                              hipStream_t stream) {
    const float* imgs  = (const float*)d_in[0];   // [16][64][64][64] f32
    const float* filts = (const float*)d_in[1];   // [1][64][64][3][3][2] f32
    float* out = (float*)d_out;                   // [16][64][64][64] f32
    (void)d_ws; (void)ws_size;                    // no workspace needed

    hipLaunchKernelGGL(conv_one, dim3(256), dim3(512), 0, stream, imgs, filts, out);
}